// Round 1
// baseline (552.847 us; speedup 1.0000x reference)
//
#include <hip/hip_runtime.h>

// ---------------------------------------------------------------------------
// CrossAttention: out = softmax((x Wq)(ctx Wk)^T / sqrt(DH) + mask) (ctx Wv) Wo + bo
// B=16, NP=4096, NT=77 (padded to 96), QD=512, CD=768, H=8, DH=64, INNER=512
// Strategy: fp16 MFMA (16x16x32) everywhere, fp32 accumulate.
// ---------------------------------------------------------------------------

typedef _Float16 half_t;
typedef _Float16 half8 __attribute__((ext_vector_type(8)));
typedef float f32x4 __attribute__((ext_vector_type(4)));
typedef unsigned int u32;

#define NB 16
#define NP 4096
#define NT 77
#define NTP 96
#define QD 512
#define CD 768
#define NH 8
#define DH 64
#define INNER 512
#define MKV (NB * NT)   // 1232

__device__ __forceinline__ void stage16(const void* g, void* l) {
    __builtin_amdgcn_global_load_lds((const __attribute__((address_space(1))) u32*)g,
                                     (__attribute__((address_space(3))) u32*)l, 16, 0, 0);
}

// ---------------- transpose + fp32->fp16 convert: out[n][k] = in[k][n] -------
__global__ __launch_bounds__(256) void kTranspose(const float* __restrict__ in,
                                                  half_t* __restrict__ out,
                                                  int K, int N) {
    __shared__ float tile[32][33];
    int tx = threadIdx.x & 31, ty = threadIdx.x >> 5;  // 32 x 8
    int kb = blockIdx.y * 32, nb = blockIdx.x * 32;
    for (int r = ty; r < 32; r += 8)
        tile[r][tx] = in[(size_t)(kb + r) * N + nb + tx];
    __syncthreads();
    for (int r = ty; r < 32; r += 8)
        out[(size_t)(nb + r) * K + kb + tx] = (half_t)tile[tx][r];
}

// ---------------- elementwise fp32 -> fp16 ----------------------------------
__global__ __launch_bounds__(256) void kConvert(const float* __restrict__ in,
                                                half_t* __restrict__ out, int n) {
    for (int i = blockIdx.x * 256 + threadIdx.x; i < n; i += gridDim.x * 256)
        out[i] = (half_t)in[i];
}

// ---------------- K/V projection GEMM (M=1232, K=768, N=512, z selects Wk/Wv)
__global__ __launch_bounds__(256) void kKVproj(const half_t* __restrict__ Ctx,
                                               const half_t* __restrict__ WkT,
                                               const half_t* __restrict__ WvT,
                                               half_t* __restrict__ Kp,
                                               half_t* __restrict__ VTp) {
    __shared__ alignas(16) half_t As[128 * 32];
    __shared__ alignas(16) half_t Bs[128 * 32];
    const int t = threadIdx.x, w = t >> 6, lane = t & 63;
    const int c0 = lane & 15, q4 = lane >> 4;
    const int wm = w & 1, wn = w >> 1;
    const int m0 = blockIdx.y * 128, n0 = blockIdx.x * 128;
    const int z = blockIdx.z;
    const half_t* WT = z ? WvT : WkT;

    f32x4 acc[4][4] = {};
    for (int k0 = 0; k0 < CD; k0 += 32) {
        for (int q = 0; q < 2; ++q) {
            int c = q * 256 + t;
            int m = c >> 2, h8 = (c & 3) * 8;
            int row = m0 + m; if (row > MKV - 1) row = MKV - 1;
            stage16(Ctx + (size_t)row * CD + k0 + h8, &As[(q * 256 + w * 64) * 8]);
        }
        for (int q = 0; q < 2; ++q) {
            int c = q * 256 + t;
            int n = c >> 2, h8 = (c & 3) * 8;
            stage16(WT + (size_t)(n0 + n) * CD + k0 + h8, &Bs[(q * 256 + w * 64) * 8]);
        }
        __syncthreads();
        half8 a[4];
        for (int i = 0; i < 4; ++i)
            a[i] = *(const half8*)&As[(wm * 64 + 16 * i + c0) * 32 + q4 * 8];
        for (int j = 0; j < 4; ++j) {
            half8 bv = *(const half8*)&Bs[(wn * 64 + 16 * j + c0) * 32 + q4 * 8];
            for (int i = 0; i < 4; ++i)
                acc[i][j] = __builtin_amdgcn_mfma_f32_16x16x32_f16(a[i], bv, acc[i][j], 0, 0, 0);
        }
        __syncthreads();
    }
    for (int i = 0; i < 4; ++i)
        for (int j = 0; j < 4; ++j)
            for (int r = 0; r < 4; ++r) {
                int row = m0 + wm * 64 + 16 * i + q4 * 4 + r;
                if (row >= MKV) continue;
                int col = n0 + wn * 64 + 16 * j + c0;
                int b = row / NT, tt = row - b * NT;
                int h = col >> 6, d = col & 63;
                half_t v = (half_t)acc[i][j][r];
                if (!z) Kp[(((size_t)b * NH + h) * NTP + tt) * DH + d] = v;
                else    VTp[(((size_t)b * NH + h) * DH + d) * NTP + tt] = v;
            }
}

// ---------------- Q projection: Q = x(fp32) @ WqT^T  (M=65536,K=512,N=512) --
__global__ __launch_bounds__(256) void kQproj(const float* __restrict__ X,
                                              const half_t* __restrict__ WqT,
                                              half_t* __restrict__ Q) {
    __shared__ alignas(16) float Asf[128 * 32];
    __shared__ alignas(16) half_t Bs[128 * 32];
    const int t = threadIdx.x, w = t >> 6, lane = t & 63;
    const int c0 = lane & 15, q4 = lane >> 4;
    const int wm = w & 1, wn = w >> 1;
    const int m0 = blockIdx.y * 128, n0 = blockIdx.x * 128;

    f32x4 acc[4][4] = {};
    for (int k0 = 0; k0 < QD; k0 += 32) {
        for (int q = 0; q < 4; ++q) {   // A tile fp32: 1024 x 16B chunks
            int c = q * 256 + t;
            int m = c >> 3, f4 = (c & 7) * 4;
            stage16(X + (size_t)(m0 + m) * QD + k0 + f4, &Asf[(q * 256 + w * 64) * 4]);
        }
        for (int q = 0; q < 2; ++q) {   // B tile fp16: 512 chunks
            int c = q * 256 + t;
            int n = c >> 2, h8 = (c & 3) * 8;
            stage16(WqT + (size_t)(n0 + n) * QD + k0 + h8, &Bs[(q * 256 + w * 64) * 8]);
        }
        __syncthreads();
        half8 a[4];
        for (int i = 0; i < 4; ++i) {
            const f32x4* ap = (const f32x4*)&Asf[(wm * 64 + 16 * i + c0) * 32 + q4 * 8];
            f32x4 a0 = ap[0], a1 = ap[1];
            half8 av;
            for (int e = 0; e < 4; ++e) { av[e] = (half_t)a0[e]; av[4 + e] = (half_t)a1[e]; }
            a[i] = av;
        }
        for (int j = 0; j < 4; ++j) {
            half8 bv = *(const half8*)&Bs[(wn * 64 + 16 * j + c0) * 32 + q4 * 8];
            for (int i = 0; i < 4; ++i)
                acc[i][j] = __builtin_amdgcn_mfma_f32_16x16x32_f16(a[i], bv, acc[i][j], 0, 0, 0);
        }
        __syncthreads();
    }
    for (int i = 0; i < 4; ++i)
        for (int j = 0; j < 4; ++j)
            for (int r = 0; r < 4; ++r) {
                int row = m0 + wm * 64 + 16 * i + q4 * 4 + r;
                int col = n0 + wn * 64 + 16 * j + c0;
                Q[(size_t)row * INNER + col] = (half_t)acc[i][j][r];
            }
}

// ---------------- fused attention per (qtile=128, h, b); AO overwrites Q ----
__global__ __launch_bounds__(256) void kAttn(half_t* __restrict__ Q,
                                             const half_t* __restrict__ Kp,
                                             const half_t* __restrict__ VTp,
                                             const int* __restrict__ mask) {
    __shared__ alignas(16) half_t Qs[128 * 104];   // stride 104; reused as P
    __shared__ alignas(16) half_t Ks[NTP * 72];    // stride 72
    __shared__ alignas(16) half_t VTs[DH * 104];   // stride 104
    const int t = threadIdx.x, w = t >> 6, lane = t & 63;
    const int c0 = lane & 15, q4 = lane >> 4;
    const int qt = blockIdx.x, h = blockIdx.y, b = blockIdx.z;
    const int q0 = qt * 128;
    const size_t qbase = ((size_t)b * NP + q0) * INNER + h * DH;

    // stage Q tile (128x64), K (96x64), VT (64x96)
    for (int q = 0; q < 4; ++q) {
        int c = q * 256 + t, m = c >> 3, k8 = (c & 7) * 8;
        *(uint4*)&Qs[m * 104 + k8] = *(const uint4*)(Q + qbase + (size_t)m * INNER + k8);
    }
    const half_t* Kh = Kp + ((size_t)b * NH + h) * NTP * DH;
    for (int q = 0; q < 3; ++q) {
        int c = q * 256 + t, r = c >> 3, k8 = (c & 7) * 8;
        *(uint4*)&Ks[r * 72 + k8] = *(const uint4*)(Kh + r * DH + k8);
    }
    const half_t* Vh = VTp + ((size_t)b * NH + h) * DH * NTP;
    for (int q = 0; q < 3; ++q) {
        int c = q * 256 + t, r = c / 12, t8 = (c % 12) * 8;
        *(uint4*)&VTs[r * 104 + t8] = *(const uint4*)(Vh + r * NTP + t8);
    }
    __syncthreads();

    // scores: wave's 32 rows x 96 cols, K=64
    const int r0 = w * 32;
    f32x4 sacc[2][6] = {};
    for (int ks = 0; ks < 2; ++ks) {
        half8 a0 = *(const half8*)&Qs[(r0 + c0) * 104 + ks * 32 + q4 * 8];
        half8 a1 = *(const half8*)&Qs[(r0 + 16 + c0) * 104 + ks * 32 + q4 * 8];
        for (int j = 0; j < 6; ++j) {
            half8 bv = *(const half8*)&Ks[(16 * j + c0) * 72 + ks * 32 + q4 * 8];
            sacc[0][j] = __builtin_amdgcn_mfma_f32_16x16x32_f16(a0, bv, sacc[0][j], 0, 0, 0);
            sacc[1][j] = __builtin_amdgcn_mfma_f32_16x16x32_f16(a1, bv, sacc[1][j], 0, 0, 0);
        }
    }

    // mask + softmax per row; write P (fp16) into Qs region (own rows only)
    for (int i = 0; i < 2; ++i)
        for (int r = 0; r < 4; ++r) {
            int qrow = r0 + 16 * i + q4 * 4 + r;
            const int* mrow = mask + ((size_t)b * NP + q0 + qrow) * NT;
            float sv[6];
            for (int j = 0; j < 6; ++j) {
                int tt = 16 * j + c0;
                float s = sacc[i][j][r] * 0.125f;
                bool valid = (tt < NT) && (mrow[tt < NT ? tt : NT - 1] != 0);
                sv[j] = valid ? s : -1e30f;
            }
            float mx = sv[0];
            for (int j = 1; j < 6; ++j) mx = fmaxf(mx, sv[j]);
            for (int d = 1; d < 16; d <<= 1) mx = fmaxf(mx, __shfl_xor(mx, d));
            float pv[6], sum = 0.f;
            for (int j = 0; j < 6; ++j) { pv[j] = __expf(sv[j] - mx); sum += pv[j]; }
            for (int d = 1; d < 16; d <<= 1) sum += __shfl_xor(sum, d);
            float inv = 1.0f / sum;
            for (int j = 0; j < 6; ++j)
                Qs[qrow * 104 + 16 * j + c0] = (half_t)(pv[j] * inv);
        }
    __syncthreads();

    // PV: wave's 32 rows x 64 cols, K=96
    f32x4 oacc[2][4] = {};
    for (int ks = 0; ks < 3; ++ks) {
        half8 a0 = *(const half8*)&Qs[(r0 + c0) * 104 + ks * 32 + q4 * 8];
        half8 a1 = *(const half8*)&Qs[(r0 + 16 + c0) * 104 + ks * 32 + q4 * 8];
        for (int j = 0; j < 4; ++j) {
            half8 bv = *(const half8*)&VTs[(16 * j + c0) * 104 + ks * 32 + q4 * 8];
            oacc[0][j] = __builtin_amdgcn_mfma_f32_16x16x32_f16(a0, bv, oacc[0][j], 0, 0, 0);
            oacc[1][j] = __builtin_amdgcn_mfma_f32_16x16x32_f16(a1, bv, oacc[1][j], 0, 0, 0);
        }
    }
    // write AO in place of Q (disjoint per block)
    for (int i = 0; i < 2; ++i)
        for (int j = 0; j < 4; ++j)
            for (int r = 0; r < 4; ++r) {
                int qrow = r0 + 16 * i + q4 * 4 + r;
                int d = 16 * j + c0;
                Q[qbase + (size_t)qrow * INNER + d] = (half_t)oacc[i][j][r];
            }
}

// ---------------- output projection: out = AO @ WoT^T + bo (fp32 out) -------
__global__ __launch_bounds__(256) void kOproj(const half_t* __restrict__ AO,
                                              const half_t* __restrict__ WoT,
                                              const float* __restrict__ bo,
                                              float* __restrict__ out) {
    __shared__ alignas(16) half_t As[128 * 32];
    __shared__ alignas(16) half_t Bs[128 * 32];
    const int t = threadIdx.x, w = t >> 6, lane = t & 63;
    const int c0 = lane & 15, q4 = lane >> 4;
    const int wm = w & 1, wn = w >> 1;
    const int m0 = blockIdx.y * 128, n0 = blockIdx.x * 128;

    float bj[4];
    for (int j = 0; j < 4; ++j) bj[j] = bo[n0 + wn * 64 + 16 * j + c0];

    f32x4 acc[4][4] = {};
    for (int k0 = 0; k0 < INNER; k0 += 32) {
        for (int q = 0; q < 2; ++q) {
            int c = q * 256 + t;
            int m = c >> 2, h8 = (c & 3) * 8;
            stage16(AO + (size_t)(m0 + m) * INNER + k0 + h8, &As[(q * 256 + w * 64) * 8]);
        }
        for (int q = 0; q < 2; ++q) {
            int c = q * 256 + t;
            int n = c >> 2, h8 = (c & 3) * 8;
            stage16(WoT + (size_t)(n0 + n) * INNER + k0 + h8, &Bs[(q * 256 + w * 64) * 8]);
        }
        __syncthreads();
        half8 a[4];
        for (int i = 0; i < 4; ++i)
            a[i] = *(const half8*)&As[(wm * 64 + 16 * i + c0) * 32 + q4 * 8];
        for (int j = 0; j < 4; ++j) {
            half8 bv = *(const half8*)&Bs[(wn * 64 + 16 * j + c0) * 32 + q4 * 8];
            for (int i = 0; i < 4; ++i)
                acc[i][j] = __builtin_amdgcn_mfma_f32_16x16x32_f16(a[i], bv, acc[i][j], 0, 0, 0);
        }
        __syncthreads();
    }
    for (int i = 0; i < 4; ++i)
        for (int j = 0; j < 4; ++j)
            for (int r = 0; r < 4; ++r) {
                int row = m0 + wm * 64 + 16 * i + q4 * 4 + r;
                int col = n0 + wn * 64 + 16 * j + c0;
                out[(size_t)row * QD + col] = acc[i][j][r] + bj[j];
            }
}

// ---------------------------------------------------------------------------
extern "C" void kernel_launch(void* const* d_in, const int* in_sizes, int n_in,
                              void* d_out, int out_size, void* d_ws, size_t ws_size,
                              hipStream_t stream) {
    const float* x   = (const float*)d_in[0];
    const float* ctx = (const float*)d_in[1];
    const int*   msk = (const int*)d_in[2];
    const float* Wq  = (const float*)d_in[3];
    const float* Wk  = (const float*)d_in[4];
    const float* Wv  = (const float*)d_in[5];
    const float* Wo  = (const float*)d_in[6];
    const float* bo  = (const float*)d_in[7];
    float* out = (float*)d_out;

    // workspace layout (fp16 elements)
    half_t* Qws = (half_t*)d_ws;                       // 65536*512
    half_t* WqT = Qws + (size_t)NB * NP * INNER;       // 512*512
    half_t* WoT = WqT + (size_t)QD * INNER;            // 512*512
    half_t* WkT = WoT + (size_t)INNER * QD;            // 512*768
    half_t* WvT = WkT + (size_t)INNER * CD;            // 512*768
    half_t* Ctx = WvT + (size_t)INNER * CD;            // 1232*768
    half_t* Kp  = Ctx + (size_t)MKV * CD;              // 16*8*96*64
    half_t* VTp = Kp + (size_t)NB * NH * NTP * DH;     // 16*8*64*96

    kTranspose<<<dim3(INNER / 32, QD / 32), 256, 0, stream>>>(Wq, WqT, QD, INNER);
    kTranspose<<<dim3(QD / 32, INNER / 32), 256, 0, stream>>>(Wo, WoT, INNER, QD);
    kTranspose<<<dim3(INNER / 32, CD / 32), 256, 0, stream>>>(Wk, WkT, CD, INNER);
    kTranspose<<<dim3(INNER / 32, CD / 32), 256, 0, stream>>>(Wv, WvT, CD, INNER);
    kConvert<<<512, 256, 0, stream>>>(ctx, Ctx, MKV * CD);
    hipMemsetAsync(Kp, 0, (size_t)NB * NH * (NTP * DH + DH * NTP) * sizeof(half_t), stream);
    kKVproj<<<dim3(4, 10, 2), 256, 0, stream>>>(Ctx, WkT, WvT, Kp, VTp);
    kQproj<<<dim3(INNER / 128, NB * NP / 128), 256, 0, stream>>>(x, WqT, Qws);
    kAttn<<<dim3(NP / 128, NH, NB), 256, 0, stream>>>(Qws, Kp, VTp, msk);
    kOproj<<<dim3(QD / 128, NB * NP / 128), 256, 0, stream>>>(Qws, WoT, bo, out);
}

// Round 2
// 443.274 us; speedup vs baseline: 1.2472x; 1.2472x over previous
//
#include <hip/hip_runtime.h>

// ---------------------------------------------------------------------------
// CrossAttention: out = softmax((x Wq)(ctx Wk)^T / sqrt(DH) + mask) (ctx Wv) Wo + bo
// B=16, NP=4096, NT=77 (padded to 96), QD=512, CD=768, H=8, DH=64, INNER=512
// fp16 MFMA (16x16x32), fp32 accumulate. fp32->fp16 converts fused into staging.
// ---------------------------------------------------------------------------

typedef _Float16 half_t;
typedef _Float16 half8 __attribute__((ext_vector_type(8)));
typedef float f32x4 __attribute__((ext_vector_type(4)));
typedef unsigned int u32;

#define NB 16
#define NP 4096
#define NT 77
#define NTP 96
#define QD 512
#define CD 768
#define NH 8
#define DH 64
#define INNER 512
#define MKV (NB * NT)   // 1232

__device__ __forceinline__ void stage16(const void* g, void* l) {
    __builtin_amdgcn_global_load_lds((const __attribute__((address_space(1))) u32*)g,
                                     (__attribute__((address_space(3))) u32*)l, 16, 0, 0);
}

__device__ __forceinline__ f32x4 mfma16(half8 a, half8 b, f32x4 c) {
    return __builtin_amdgcn_mfma_f32_16x16x32_f16(a, b, c, 0, 0, 0);
}

// ---------------- paired transpose + fp32->fp16: out[n][k] = in[k][n] -------
__global__ __launch_bounds__(256) void kTrans2(const float* __restrict__ in0,
                                               const float* __restrict__ in1,
                                               half_t* __restrict__ out0,
                                               half_t* __restrict__ out1,
                                               int K, int N) {
    const float* in = blockIdx.z ? in1 : in0;
    half_t* out = blockIdx.z ? out1 : out0;
    __shared__ float tile[32][33];
    int tx = threadIdx.x & 31, ty = threadIdx.x >> 5;  // 32 x 8
    int kb = blockIdx.y * 32, nb = blockIdx.x * 32;
    for (int r = ty; r < 32; r += 8)
        tile[r][tx] = in[(size_t)(kb + r) * N + nb + tx];
    __syncthreads();
    for (int r = ty; r < 32; r += 8)
        out[(size_t)(nb + r) * K + kb + tx] = (half_t)tile[tx][r];
}

// ---------------- K/V projection GEMM, fused N=1024, BK=96 ------------------
// M=1232 (pad 1280, 64-row tiles), cols 0..511 -> K proj, 512..1023 -> V proj
__global__ __launch_bounds__(256) void kKVproj(const float* __restrict__ Ctx,
                                               const half_t* __restrict__ WkT,
                                               const half_t* __restrict__ WvT,
                                               half_t* __restrict__ Kp,
                                               half_t* __restrict__ VTp) {
    __shared__ alignas(16) half_t As[64 * 96];
    __shared__ alignas(16) half_t Bs[128 * 96];
    const int t = threadIdx.x, w = t >> 6, lane = t & 63;
    const int c0 = lane & 15, q4 = lane >> 4;
    const int m0 = blockIdx.y * 64;
    const int n0g = blockIdx.x * 128;
    const int z = n0g >= 512;
    const int n0 = n0g - z * 512;
    const half_t* WT = z ? WvT : WkT;

    f32x4 acc[4][2] = {};
    for (int k0 = 0; k0 < CD; k0 += 96) {
        // A: ctx fp32 -> fp16 via registers; 64x96 = 768 half8-chunks, 3/thread
        for (int q = 0; q < 3; ++q) {
            int u = q * 256 + t;
            int row = u / 12, h8 = (u % 12) * 8;
            int gr = m0 + row; if (gr > MKV - 1) gr = MKV - 1;
            const float* src = Ctx + (size_t)gr * CD + k0 + h8;
            f32x4 f0 = *(const f32x4*)src;
            f32x4 f1 = *(const f32x4*)(src + 4);
            half8 hv;
            for (int e = 0; e < 4; ++e) { hv[e] = (half_t)f0[e]; hv[4 + e] = (half_t)f1[e]; }
            *(half8*)&As[row * 96 + h8] = hv;
        }
        // B: fp16 weights via global_load_lds; 128x96 = 1536 chunks, 6/thread
        for (int q = 0; q < 6; ++q) {
            int c = q * 256 + t;
            stage16(WT + (size_t)(n0 + c / 12) * CD + k0 + (c % 12) * 8, &Bs[c * 8]);
        }
        __syncthreads();
        for (int ks = 0; ks < 3; ++ks) {
            half8 a[4], b[2];
            for (int i = 0; i < 4; ++i)
                a[i] = *(const half8*)&As[(16 * i + c0) * 96 + ks * 32 + q4 * 8];
            for (int j = 0; j < 2; ++j)
                b[j] = *(const half8*)&Bs[(w * 32 + 16 * j + c0) * 96 + ks * 32 + q4 * 8];
            for (int i = 0; i < 4; ++i)
                for (int j = 0; j < 2; ++j)
                    acc[i][j] = mfma16(a[i], b[j], acc[i][j]);
        }
        __syncthreads();
    }
    for (int i = 0; i < 4; ++i)
        for (int j = 0; j < 2; ++j)
            for (int r = 0; r < 4; ++r) {
                int row = m0 + 16 * i + q4 * 4 + r;
                if (row >= MKV) continue;
                int col = n0 + w * 32 + 16 * j + c0;
                int b = row / NT, tt = row - b * NT;
                int h = col >> 6, d = col & 63;
                half_t v = (half_t)acc[i][j][r];
                if (!z) Kp[(((size_t)b * NH + h) * NTP + tt) * DH + d] = v;
                else    VTp[(((size_t)b * NH + h) * DH + d) * NTP + tt] = v;
            }
}

// ---------------- Q projection: Q = x(fp32) @ WqT^T  (M=65536,K=512,N=512) --
__global__ __launch_bounds__(256) void kQproj(const float* __restrict__ X,
                                              const half_t* __restrict__ WqT,
                                              half_t* __restrict__ Q) {
    __shared__ alignas(16) half_t As[128 * 32];
    __shared__ alignas(16) half_t Bs[128 * 32];
    const int t = threadIdx.x, w = t >> 6, lane = t & 63;
    const int c0 = lane & 15, q4 = lane >> 4;
    const int wm = w & 1, wn = w >> 1;
    const int m0 = blockIdx.y * 128, n0 = blockIdx.x * 128;

    f32x4 acc[4][4] = {};
    for (int k0 = 0; k0 < QD; k0 += 32) {
        // A: x fp32 -> fp16 via registers; 128x32 = 512 half8-chunks, 2/thread
        for (int q = 0; q < 2; ++q) {
            int u = q * 256 + t;
            int row = u >> 2, h8 = (u & 3) * 8;
            const float* src = X + (size_t)(m0 + row) * QD + k0 + h8;
            f32x4 f0 = *(const f32x4*)src;
            f32x4 f1 = *(const f32x4*)(src + 4);
            half8 hv;
            for (int e = 0; e < 4; ++e) { hv[e] = (half_t)f0[e]; hv[4 + e] = (half_t)f1[e]; }
            *(half8*)&As[row * 32 + h8] = hv;
        }
        // B: fp16 weights via global_load_lds
        for (int q = 0; q < 2; ++q) {
            int c = q * 256 + t;
            stage16(WqT + (size_t)(n0 + (c >> 2)) * QD + k0 + (c & 3) * 8, &Bs[c * 8]);
        }
        __syncthreads();
        half8 a[4];
        for (int i = 0; i < 4; ++i)
            a[i] = *(const half8*)&As[(wm * 64 + 16 * i + c0) * 32 + q4 * 8];
        for (int j = 0; j < 4; ++j) {
            half8 bv = *(const half8*)&Bs[(wn * 64 + 16 * j + c0) * 32 + q4 * 8];
            for (int i = 0; i < 4; ++i)
                acc[i][j] = mfma16(a[i], bv, acc[i][j]);
        }
        __syncthreads();
    }
    for (int i = 0; i < 4; ++i)
        for (int j = 0; j < 4; ++j)
            for (int r = 0; r < 4; ++r) {
                int row = m0 + wm * 64 + 16 * i + q4 * 4 + r;
                int col = n0 + wn * 64 + 16 * j + c0;
                Q[(size_t)row * INNER + col] = (half_t)acc[i][j][r];
            }
}

// ---------------- fused attention per (qtile=128, h, b); AO overwrites Q ----
__global__ __launch_bounds__(256) void kAttn(half_t* __restrict__ Q,
                                             const half_t* __restrict__ Kp,
                                             const half_t* __restrict__ VTp,
                                             const int* __restrict__ mask) {
    __shared__ alignas(16) half_t Qs[128 * 104];   // stride 104; reused as P
    __shared__ alignas(16) half_t Ks[NTP * 72];    // stride 72
    __shared__ alignas(16) half_t VTs[DH * 104];   // stride 104
    const int t = threadIdx.x, w = t >> 6, lane = t & 63;
    const int c0 = lane & 15, q4 = lane >> 4;
    const int qt = blockIdx.x, h = blockIdx.y, b = blockIdx.z;
    const int q0 = qt * 128;
    const size_t qbase = ((size_t)b * NP + q0) * INNER + h * DH;

    for (int q = 0; q < 4; ++q) {
        int c = q * 256 + t, m = c >> 3, k8 = (c & 7) * 8;
        *(uint4*)&Qs[m * 104 + k8] = *(const uint4*)(Q + qbase + (size_t)m * INNER + k8);
    }
    const half_t* Kh = Kp + ((size_t)b * NH + h) * NTP * DH;
    for (int q = 0; q < 3; ++q) {
        int c = q * 256 + t, r = c >> 3, k8 = (c & 7) * 8;
        *(uint4*)&Ks[r * 72 + k8] = *(const uint4*)(Kh + r * DH + k8);
    }
    const half_t* Vh = VTp + ((size_t)b * NH + h) * DH * NTP;
    for (int q = 0; q < 3; ++q) {
        int c = q * 256 + t, r = c / 12, t8 = (c % 12) * 8;
        *(uint4*)&VTs[r * 104 + t8] = *(const uint4*)(Vh + r * NTP + t8);
    }
    __syncthreads();

    const int r0 = w * 32;
    f32x4 sacc[2][6] = {};
    for (int ks = 0; ks < 2; ++ks) {
        half8 a0 = *(const half8*)&Qs[(r0 + c0) * 104 + ks * 32 + q4 * 8];
        half8 a1 = *(const half8*)&Qs[(r0 + 16 + c0) * 104 + ks * 32 + q4 * 8];
        for (int j = 0; j < 6; ++j) {
            half8 bv = *(const half8*)&Ks[(16 * j + c0) * 72 + ks * 32 + q4 * 8];
            sacc[0][j] = mfma16(a0, bv, sacc[0][j]);
            sacc[1][j] = mfma16(a1, bv, sacc[1][j]);
        }
    }

    for (int i = 0; i < 2; ++i)
        for (int r = 0; r < 4; ++r) {
            int qrow = r0 + 16 * i + q4 * 4 + r;
            const int* mrow = mask + ((size_t)b * NP + q0 + qrow) * NT;
            float sv[6];
            for (int j = 0; j < 6; ++j) {
                int tt = 16 * j + c0;
                float s = sacc[i][j][r] * 0.125f;
                bool valid = (tt < NT) && (mrow[tt < NT ? tt : NT - 1] != 0);
                sv[j] = valid ? s : -1e30f;
            }
            float mx = sv[0];
            for (int j = 1; j < 6; ++j) mx = fmaxf(mx, sv[j]);
            for (int d = 1; d < 16; d <<= 1) mx = fmaxf(mx, __shfl_xor(mx, d));
            float pv[6], sum = 0.f;
            for (int j = 0; j < 6; ++j) { pv[j] = __expf(sv[j] - mx); sum += pv[j]; }
            for (int d = 1; d < 16; d <<= 1) sum += __shfl_xor(sum, d);
            float inv = 1.0f / sum;
            for (int j = 0; j < 6; ++j)
                Qs[qrow * 104 + 16 * j + c0] = (half_t)(pv[j] * inv);
        }
    __syncthreads();

    f32x4 oacc[2][4] = {};
    for (int ks = 0; ks < 3; ++ks) {
        half8 a0 = *(const half8*)&Qs[(r0 + c0) * 104 + ks * 32 + q4 * 8];
        half8 a1 = *(const half8*)&Qs[(r0 + 16 + c0) * 104 + ks * 32 + q4 * 8];
        for (int j = 0; j < 4; ++j) {
            half8 bv = *(const half8*)&VTs[(16 * j + c0) * 104 + ks * 32 + q4 * 8];
            oacc[0][j] = mfma16(a0, bv, oacc[0][j]);
            oacc[1][j] = mfma16(a1, bv, oacc[1][j]);
        }
    }
    for (int i = 0; i < 2; ++i)
        for (int j = 0; j < 4; ++j)
            for (int r = 0; r < 4; ++r) {
                int qrow = r0 + 16 * i + q4 * 4 + r;
                int d = 16 * j + c0;
                Q[qbase + (size_t)qrow * INNER + d] = (half_t)oacc[i][j][r];
            }
}

// ---------------- output projection: out = AO @ WoT^T + bo (fp32 out) -------
__global__ __launch_bounds__(256) void kOproj(const half_t* __restrict__ AO,
                                              const half_t* __restrict__ WoT,
                                              const float* __restrict__ bo,
                                              float* __restrict__ out) {
    __shared__ alignas(16) half_t As[128 * 32];
    __shared__ alignas(16) half_t Bs[128 * 32];
    const int t = threadIdx.x, w = t >> 6, lane = t & 63;
    const int c0 = lane & 15, q4 = lane >> 4;
    const int wm = w & 1, wn = w >> 1;
    const int m0 = blockIdx.y * 128, n0 = blockIdx.x * 128;

    float bj[4];
    for (int j = 0; j < 4; ++j) bj[j] = bo[n0 + wn * 64 + 16 * j + c0];

    f32x4 acc[4][4] = {};
    for (int k0 = 0; k0 < INNER; k0 += 32) {
        for (int q = 0; q < 2; ++q) {
            int c = q * 256 + t;
            stage16(AO + (size_t)(m0 + (c >> 2)) * INNER + k0 + (c & 3) * 8, &As[c * 8]);
        }
        for (int q = 0; q < 2; ++q) {
            int c = q * 256 + t;
            stage16(WoT + (size_t)(n0 + (c >> 2)) * INNER + k0 + (c & 3) * 8, &Bs[c * 8]);
        }
        __syncthreads();
        half8 a[4];
        for (int i = 0; i < 4; ++i)
            a[i] = *(const half8*)&As[(wm * 64 + 16 * i + c0) * 32 + q4 * 8];
        for (int j = 0; j < 4; ++j) {
            half8 bv = *(const half8*)&Bs[(wn * 64 + 16 * j + c0) * 32 + q4 * 8];
            for (int i = 0; i < 4; ++i)
                acc[i][j] = mfma16(a[i], bv, acc[i][j]);
        }
        __syncthreads();
    }
    for (int i = 0; i < 4; ++i)
        for (int j = 0; j < 4; ++j)
            for (int r = 0; r < 4; ++r) {
                int row = m0 + wm * 64 + 16 * i + q4 * 4 + r;
                int col = n0 + wn * 64 + 16 * j + c0;
                out[(size_t)row * QD + col] = acc[i][j][r] + bj[j];
            }
}

// ---------------------------------------------------------------------------
extern "C" void kernel_launch(void* const* d_in, const int* in_sizes, int n_in,
                              void* d_out, int out_size, void* d_ws, size_t ws_size,
                              hipStream_t stream) {
    const float* x   = (const float*)d_in[0];
    const float* ctx = (const float*)d_in[1];
    const int*   msk = (const int*)d_in[2];
    const float* Wq  = (const float*)d_in[3];
    const float* Wk  = (const float*)d_in[4];
    const float* Wv  = (const float*)d_in[5];
    const float* Wo  = (const float*)d_in[6];
    const float* bo  = (const float*)d_in[7];
    float* out = (float*)d_out;

    half_t* Qws = (half_t*)d_ws;                       // 65536*512
    half_t* WqT = Qws + (size_t)NB * NP * INNER;       // 512*512
    half_t* WoT = WqT + (size_t)QD * INNER;            // 512*512
    half_t* WkT = WoT + (size_t)INNER * QD;            // 512*768
    half_t* WvT = WkT + (size_t)INNER * CD;            // 512*768
    half_t* Kp  = WvT + (size_t)INNER * CD;            // 16*8*96*64
    half_t* VTp = Kp + (size_t)NB * NH * NTP * DH;     // 16*8*64*96

    kTrans2<<<dim3(INNER / 32, QD / 32, 2), 256, 0, stream>>>(Wq, Wo, WqT, WoT, QD, INNER);
    kTrans2<<<dim3(INNER / 32, CD / 32, 2), 256, 0, stream>>>(Wk, Wv, WkT, WvT, CD, INNER);
    hipMemsetAsync(Kp, 0, (size_t)NB * NH * (NTP * DH + DH * NTP) * sizeof(half_t), stream);
    kKVproj<<<dim3(8, 20), 256, 0, stream>>>(ctx, WkT, WvT, Kp, VTp);
    kQproj<<<dim3(INNER / 128, NB * NP / 128), 256, 0, stream>>>(x, WqT, Qws);
    kAttn<<<dim3(NP / 128, NH, NB), 256, 0, stream>>>(Qws, Kp, VTp, msk);
    kOproj<<<dim3(QD / 128, NB * NP / 128), 256, 0, stream>>>(Qws, WoT, bo, out);
}